// Round 1
// baseline (352.699 us; speedup 1.0000x reference)
//
#include <hip/hip_runtime.h>

#define NB 8
#define SL 128
#define HD 768

// Kernel 1: pack valid tokens -> hidden[b,i,:] = seq[b,src_i,:]*aspect[b,i];
// gather key embeddings with padding_idx=0 zeroed.
__global__ __launch_bounds__(256) void k_pack_gather(
    const float* __restrict__ seq,
    const float* __restrict__ W_key,
    const int* __restrict__ valid,
    const int* __restrict__ kvidx,
    const int* __restrict__ aspect,
    float* __restrict__ hidden,
    float* __restrict__ keyemb) {
  int b = blockIdx.x;
  int tid = threadIdx.x;
  __shared__ int s_src[SL];
  __shared__ int s_count;
  if (tid == 0) {
    int c = 0;
    for (int j = 0; j < SL; ++j)
      if (valid[b * SL + j] != 0) s_src[c++] = j;
    s_count = c;
  }
  __syncthreads();
  int count = s_count;
  for (int idx = tid; idx < SL * HD; idx += 256) {
    int i = idx / HD;
    int h = idx - i * HD;
    float v = 0.f;
    if (i < count) {
      v = seq[((size_t)(b * SL + s_src[i])) * HD + h] * (float)aspect[b * SL + i];
    }
    hidden[((size_t)(b * SL + i)) * HD + h] = v;
  }
  for (int idx = tid; idx < SL * HD; idx += 256) {
    int k = idx / HD;
    int h = idx - k * HD;
    int id = kvidx[b * SL + k];
    keyemb[((size_t)(b * SL + k)) * HD + h] = (id == 0) ? 0.f : W_key[(size_t)id * HD + h];
  }
}

// Kernel 2: per (b,q) block: u = hidden.key/sqrt(H); delta = exp(u)*pos;
// p = delta/(sum+1e-10); o = sum_k p[k]*W_val[features[b,q,k],:]
__global__ __launch_bounds__(256) void k_attend(
    const float* __restrict__ hidden,
    const float* __restrict__ keyemb,
    const int* __restrict__ features,
    const int* __restrict__ pos,
    const float* __restrict__ W_val,
    float* __restrict__ o) {
  int bq = blockIdx.x;
  int b = bq >> 7;
  int tid = threadIdx.x;
  int wave = tid >> 6, lane = tid & 63;
  __shared__ float s_h[HD];
  __shared__ float s_p[SL];
  __shared__ int s_f[SL];
  __shared__ float s_sum;
  for (int i = tid; i < HD; i += 256) s_h[i] = hidden[(size_t)bq * HD + i];
  if (tid < SL) s_f[tid] = features[(size_t)bq * SL + tid];
  __syncthreads();
  const float rscale = 0.03608439182435161f;  // 1/sqrt(768)
  for (int k = wave; k < SL; k += 4) {
    const float* kr = keyemb + ((size_t)(b * SL + k)) * HD;
    float part = 0.f;
#pragma unroll
    for (int j = 0; j < HD / 64; ++j) {
      part += kr[lane + 64 * j] * s_h[lane + 64 * j];
    }
#pragma unroll
    for (int off = 32; off; off >>= 1) part += __shfl_xor(part, off);
    if (lane == 0) s_p[k] = part * rscale;
  }
  __syncthreads();
  if (tid < SL) {
    float d = (pos[(size_t)bq * SL + tid] != 0) ? expf(s_p[tid]) : 0.f;
    s_p[tid] = d;
  }
  __syncthreads();
  if (tid == 0) {
    float s = 0.f;
    for (int k = 0; k < SL; ++k) s += s_p[k];
    s_sum = s + 1e-10f;
  }
  __syncthreads();
  if (tid < SL) s_p[tid] = s_p[tid] / s_sum;  // same op as reference
  __syncthreads();
  float a0 = 0.f, a1 = 0.f, a2 = 0.f;
  for (int k = 0; k < SL; ++k) {
    float pk = s_p[k];        // broadcast -> block-uniform branch, no divergence
    if (pk == 0.f) continue;  // pos==0 rows: ~half skipped
    int f = s_f[k];
    if (f == 0) continue;     // padding_idx row of W_val is all-zero
    const float* vr = W_val + (size_t)f * HD;
    a0 += pk * vr[tid];
    a1 += pk * vr[tid + 256];
    a2 += pk * vr[tid + 512];
  }
  float* orow = o + (size_t)bq * HD;
  orow[tid] = a0;
  orow[tid + 256] = a1;
  orow[tid + 512] = a2;
}

// Kernel 3: avg_o[b,h] = sum_q o / count_q(o != 0); logits = [pooled,avg_o]@Wd^T + b
__global__ __launch_bounds__(256) void k_head(
    const float* __restrict__ o,
    const float* __restrict__ pooled,
    const float* __restrict__ W_dense,
    const float* __restrict__ b_dense,
    float* __restrict__ out) {
  int b = blockIdx.x;
  int tid = threadIdx.x;
  __shared__ float s_avg[HD];
  for (int h = tid; h < HD; h += 256) {
    float sum = 0.f;
    int cnt = 0;
    for (int q = 0; q < SL; ++q) {
      float v = o[((size_t)(b * SL + q)) * HD + h];
      sum += v;
      cnt += (v != 0.f) ? 1 : 0;
    }
    s_avg[h] = sum / (float)cnt;  // matches reference IEEE semantics (inf/nan if cnt==0)
  }
  __syncthreads();
  int wave = tid >> 6, lane = tid & 63;
  if (wave < 3) {
    int n = wave;
    float part = 0.f;
    for (int j = lane; j < HD; j += 64)
      part += pooled[(size_t)b * HD + j] * W_dense[(size_t)n * (2 * HD) + j];
    for (int j = lane; j < HD; j += 64)
      part += s_avg[j] * W_dense[(size_t)n * (2 * HD) + HD + j];
#pragma unroll
    for (int off = 32; off; off >>= 1) part += __shfl_xor(part, off);
    if (lane == 0) out[b * 3 + n] = part + b_dense[n];
  }
}

extern "C" void kernel_launch(void* const* d_in, const int* in_sizes, int n_in,
                              void* d_out, int out_size, void* d_ws, size_t ws_size,
                              hipStream_t stream) {
  const float* seq     = (const float*)d_in[0];
  const float* pooled  = (const float*)d_in[1];
  const float* W_key   = (const float*)d_in[2];
  const float* W_val   = (const float*)d_in[3];
  const float* W_dense = (const float*)d_in[4];
  const float* b_dense = (const float*)d_in[5];
  const int* valid     = (const int*)d_in[6];
  const int* kvidx     = (const int*)d_in[7];
  const int* features  = (const int*)d_in[8];
  const int* pos       = (const int*)d_in[9];
  const int* aspect    = (const int*)d_in[10];
  float* out = (float*)d_out;

  float* hidden = (float*)d_ws;                       // [B,L,H]
  float* keyemb = hidden + (size_t)NB * SL * HD;      // [B,L,H]
  float* o      = keyemb + (size_t)NB * SL * HD;      // [B,L,H]

  k_pack_gather<<<NB, 256, 0, stream>>>(seq, W_key, valid, kvidx, aspect, hidden, keyemb);
  k_attend<<<NB * SL, 256, 0, stream>>>(hidden, keyemb, features, pos, W_val, o);
  k_head<<<NB, 256, 0, stream>>>(o, pooled, W_dense, b_dense, out);
}

// Round 2
// 107.059 us; speedup vs baseline: 3.2944x; 3.2944x over previous
//
#include <hip/hip_runtime.h>

#define NB 8
#define SL 128
#define HD 768

// Kernel 1: one block per (b,i). Computes:
//   hidden[b,i,:] = (i < count_b) ? seq[b, src_i, :] * aspect[b,i] : 0
//   keyemb[b,i,:] = (kvidx[b,i]==0) ? 0 : W_key[kvidx[b,i], :]
// src_i = position of the i-th valid token, found via wave ballot rank.
__global__ __launch_bounds__(256) void k_pack_gather(
    const float* __restrict__ seq,
    const float* __restrict__ W_key,
    const int* __restrict__ valid,
    const int* __restrict__ kvidx,
    const int* __restrict__ aspect,
    float* __restrict__ hidden,
    float* __restrict__ keyemb) {
  int bq = blockIdx.x;
  int b = bq >> 7;
  int i = bq & (SL - 1);
  int tid = threadIdx.x;
  int lane = tid & 63, wv = tid >> 6;

  __shared__ int s_wcnt[4];
  __shared__ int s_src;

  int v = (tid < SL) ? (valid[b * SL + tid] != 0) : 0;
  unsigned long long m = __ballot(v);
  if (lane == 0) s_wcnt[wv] = __popcll(m);
  if (tid == 0) s_src = SL;  // sentinel
  __syncthreads();
  int count = s_wcnt[0] + s_wcnt[1];
  if (v) {
    int rank = __popcll(m & ((1ull << lane) - 1ull)) + (wv == 1 ? s_wcnt[0] : 0);
    if (rank == i) s_src = tid;
  }
  __syncthreads();
  int src = s_src;

  if (tid < HD / 4) {  // 192 threads, one float4 each
    float4 hv = make_float4(0.f, 0.f, 0.f, 0.f);
    if (i < count && src < SL) {
      float asp = (float)aspect[b * SL + i];
      const float4* srow = (const float4*)(seq + ((size_t)(b * SL + src)) * HD);
      float4 s = srow[tid];
      hv = make_float4(s.x * asp, s.y * asp, s.z * asp, s.w * asp);
    }
    ((float4*)(hidden + (size_t)bq * HD))[tid] = hv;

    int id = kvidx[b * SL + i];
    float4 kv = make_float4(0.f, 0.f, 0.f, 0.f);
    if (id != 0) {
      kv = ((const float4*)(W_key + (size_t)id * HD))[tid];
    }
    ((float4*)(keyemb + (size_t)bq * HD))[tid] = kv;
  }
}

// Kernel 2: per (b,q) block: u = hidden.key/sqrt(H); delta = exp(u)*pos;
// p = delta/(sum+1e-10); o = sum_k p[k]*W_val[features[b,q,k],:]
__global__ __launch_bounds__(256) void k_attend(
    const float* __restrict__ hidden,
    const float* __restrict__ keyemb,
    const int* __restrict__ features,
    const int* __restrict__ pos,
    const float* __restrict__ W_val,
    float* __restrict__ o) {
  int bq = blockIdx.x;
  int b = bq >> 7;
  int tid = threadIdx.x;
  int wave = tid >> 6, lane = tid & 63;
  __shared__ float s_h[HD];
  __shared__ float s_p[SL];
  __shared__ int s_f[SL];
  __shared__ float s_sum;
  for (int i = tid; i < HD; i += 256) s_h[i] = hidden[(size_t)bq * HD + i];
  if (tid < SL) s_f[tid] = features[(size_t)bq * SL + tid];
  __syncthreads();
  const float rscale = 0.03608439182435161f;  // 1/sqrt(768)
  for (int k = wave; k < SL; k += 4) {
    const float* kr = keyemb + ((size_t)(b * SL + k)) * HD;
    float part = 0.f;
#pragma unroll
    for (int j = 0; j < HD / 64; ++j) {
      part += kr[lane + 64 * j] * s_h[lane + 64 * j];
    }
#pragma unroll
    for (int off = 32; off; off >>= 1) part += __shfl_xor(part, off);
    if (lane == 0) s_p[k] = part * rscale;
  }
  __syncthreads();
  if (tid < SL) {
    float d = (pos[(size_t)bq * SL + tid] != 0) ? expf(s_p[tid]) : 0.f;
    s_p[tid] = d;
  }
  __syncthreads();
  if (tid == 0) {
    float s = 0.f;
    for (int k = 0; k < SL; ++k) s += s_p[k];
    s_sum = s + 1e-10f;
  }
  __syncthreads();
  if (tid < SL) s_p[tid] = s_p[tid] / s_sum;  // same op as reference
  __syncthreads();
  float a0 = 0.f, a1 = 0.f, a2 = 0.f;
  for (int k = 0; k < SL; ++k) {
    float pk = s_p[k];        // broadcast -> block-uniform branch, no divergence
    if (pk == 0.f) continue;  // pos==0 rows: ~half skipped
    int f = s_f[k];
    if (f == 0) continue;     // padding_idx row of W_val is all-zero
    const float* vr = W_val + (size_t)f * HD;
    a0 += pk * vr[tid];
    a1 += pk * vr[tid + 256];
    a2 += pk * vr[tid + 512];
  }
  float* orow = o + (size_t)bq * HD;
  orow[tid] = a0;
  orow[tid + 256] = a1;
  orow[tid + 512] = a2;
}

// Kernel 3: avg_o[b,h] = sum_q o / count_q(o != 0); logits = [pooled,avg_o]@Wd^T + b
__global__ __launch_bounds__(256) void k_head(
    const float* __restrict__ o,
    const float* __restrict__ pooled,
    const float* __restrict__ W_dense,
    const float* __restrict__ b_dense,
    float* __restrict__ out) {
  int b = blockIdx.x;
  int tid = threadIdx.x;
  __shared__ float s_avg[HD];
  for (int h = tid; h < HD; h += 256) {
    float sum = 0.f;
    int cnt = 0;
    for (int q = 0; q < SL; ++q) {
      float v = o[((size_t)(b * SL + q)) * HD + h];
      sum += v;
      cnt += (v != 0.f) ? 1 : 0;
    }
    s_avg[h] = sum / (float)cnt;  // matches reference IEEE semantics
  }
  __syncthreads();
  int wave = tid >> 6, lane = tid & 63;
  if (wave < 3) {
    int n = wave;
    float part = 0.f;
    for (int j = lane; j < HD; j += 64)
      part += pooled[(size_t)b * HD + j] * W_dense[(size_t)n * (2 * HD) + j];
    for (int j = lane; j < HD; j += 64)
      part += s_avg[j] * W_dense[(size_t)n * (2 * HD) + HD + j];
#pragma unroll
    for (int off = 32; off; off >>= 1) part += __shfl_xor(part, off);
    if (lane == 0) out[b * 3 + n] = part + b_dense[n];
  }
}

extern "C" void kernel_launch(void* const* d_in, const int* in_sizes, int n_in,
                              void* d_out, int out_size, void* d_ws, size_t ws_size,
                              hipStream_t stream) {
  const float* seq     = (const float*)d_in[0];
  const float* pooled  = (const float*)d_in[1];
  const float* W_key   = (const float*)d_in[2];
  const float* W_val   = (const float*)d_in[3];
  const float* W_dense = (const float*)d_in[4];
  const float* b_dense = (const float*)d_in[5];
  const int* valid     = (const int*)d_in[6];
  const int* kvidx     = (const int*)d_in[7];
  const int* features  = (const int*)d_in[8];
  const int* pos       = (const int*)d_in[9];
  const int* aspect    = (const int*)d_in[10];
  float* out = (float*)d_out;

  float* hidden = (float*)d_ws;                       // [B,L,H]
  float* keyemb = hidden + (size_t)NB * SL * HD;      // [B,L,H]
  float* o      = keyemb + (size_t)NB * SL * HD;      // [B,L,H]

  k_pack_gather<<<NB * SL, 256, 0, stream>>>(seq, W_key, valid, kvidx, aspect, hidden, keyemb);
  k_attend<<<NB * SL, 256, 0, stream>>>(hidden, keyemb, features, pos, W_val, o);
  k_head<<<NB, 256, 0, stream>>>(o, pooled, W_dense, b_dense, out);
}

// Round 3
// 70.912 us; speedup vs baseline: 4.9738x; 1.5098x over previous
//
#include <hip/hip_runtime.h>

#define NB 8
#define SL 128
#define HD 768

// Kernel 1: one block per (b,i). hidden + keyemb gather (ballot-rank pack).
__global__ __launch_bounds__(256) void k_pack_gather(
    const float* __restrict__ seq,
    const float* __restrict__ W_key,
    const int* __restrict__ valid,
    const int* __restrict__ kvidx,
    const int* __restrict__ aspect,
    float* __restrict__ hidden,
    float* __restrict__ keyemb) {
  int bq = blockIdx.x;
  int b = bq >> 7;
  int i = bq & (SL - 1);
  int tid = threadIdx.x;
  int lane = tid & 63, wv = tid >> 6;

  __shared__ int s_wcnt[4];
  __shared__ int s_src;

  int v = (tid < SL) ? (valid[b * SL + tid] != 0) : 0;
  unsigned long long m = __ballot(v);
  if (lane == 0) s_wcnt[wv] = __popcll(m);
  if (tid == 0) s_src = SL;  // sentinel
  __syncthreads();
  int count = s_wcnt[0] + s_wcnt[1];
  if (v) {
    int rank = __popcll(m & ((1ull << lane) - 1ull)) + (wv == 1 ? s_wcnt[0] : 0);
    if (rank == i) s_src = tid;
  }
  __syncthreads();
  int src = s_src;

  if (tid < HD / 4) {  // 192 threads, one float4 each
    float4 hv = make_float4(0.f, 0.f, 0.f, 0.f);
    if (i < count && src < SL) {
      float asp = (float)aspect[b * SL + i];
      const float4* srow = (const float4*)(seq + ((size_t)(b * SL + src)) * HD);
      float4 s = srow[tid];
      hv = make_float4(s.x * asp, s.y * asp, s.z * asp, s.w * asp);
    }
    ((float4*)(hidden + (size_t)bq * HD))[tid] = hv;

    int id = kvidx[b * SL + i];
    float4 kv = make_float4(0.f, 0.f, 0.f, 0.f);
    if (id != 0) {
      kv = ((const float4*)(W_key + (size_t)id * HD))[tid];
    }
    ((float4*)(keyemb + (size_t)bq * HD))[tid] = kv;
  }
}

// Kernel 2: per (b,q) block. QK dot (float4), softmax over pos-mask,
// then compacted branch-free value gather split across 4 waves.
__global__ __launch_bounds__(256) void k_attend(
    const float* __restrict__ hidden,
    const float* __restrict__ keyemb,
    const int* __restrict__ features,
    const int* __restrict__ pos,
    const float* __restrict__ W_val,
    float* __restrict__ o) {
  int bq = blockIdx.x;
  int b = bq >> 7;
  int tid = threadIdx.x;
  int wave = tid >> 6, lane = tid & 63;

  __shared__ float4 s_h4[HD / 4];
  __shared__ float s_p[SL];
  __shared__ int s_f[SL];
  __shared__ float s_pc[SL];
  __shared__ int s_fc[SL];
  __shared__ float s_o[4][HD];
  __shared__ float s_sum;
  __shared__ int s_cnt2[2];
  __shared__ int s_m;

  if (tid < HD / 4) s_h4[tid] = ((const float4*)(hidden + (size_t)bq * HD))[tid];
  if (tid < SL) s_f[tid] = features[(size_t)bq * SL + tid];
  __syncthreads();

  const float rscale = 0.03608439182435161f;  // 1/sqrt(768)
  for (int k = wave; k < SL; k += 4) {
    const float4* kr4 = (const float4*)(keyemb + ((size_t)(b * SL + k)) * HD);
    float part = 0.f;
#pragma unroll
    for (int j = 0; j < 3; ++j) {
      float4 a = kr4[lane + 64 * j];
      float4 h = s_h4[lane + 64 * j];
      part += a.x * h.x + a.y * h.y + a.z * h.z + a.w * h.w;
    }
#pragma unroll
    for (int off = 32; off; off >>= 1) part += __shfl_xor(part, off);
    if (lane == 0) s_p[k] = part * rscale;
  }
  __syncthreads();
  if (tid < SL) {
    float d = (pos[(size_t)bq * SL + tid] != 0) ? expf(s_p[tid]) : 0.f;
    s_p[tid] = d;
  }
  __syncthreads();
  if (tid < 64) {  // wave 0 tree-reduces the denominator
    float part = s_p[tid] + s_p[tid + 64];
#pragma unroll
    for (int off = 32; off; off >>= 1) part += __shfl_xor(part, off);
    if (tid == 0) s_sum = part + 1e-10f;
  }
  __syncthreads();
  if (tid < SL) s_p[tid] = s_p[tid] / s_sum;
  __syncthreads();

  // compact surviving (p, f) pairs (branch-free gather loop after this)
  int keep = 0;
  float pv = 0.f;
  int fv = 0;
  if (tid < SL) {
    pv = s_p[tid];
    fv = s_f[tid];
    keep = (pv != 0.f) && (fv != 0);
  }
  unsigned long long km = __ballot(keep);
  if (lane == 0 && wave < 2) s_cnt2[wave] = __popcll(km);
  __syncthreads();
  if (keep) {
    int rank = __popcll(km & ((1ull << lane) - 1ull)) + (wave == 1 ? s_cnt2[0] : 0);
    s_pc[rank] = pv;
    s_fc[rank] = fv;
  }
  if (tid == 0) s_m = s_cnt2[0] + s_cnt2[1];
  __syncthreads();
  int mm = s_m;

  // each wave accumulates a full 768-wide partial over its k-slice
  float4 a0 = make_float4(0.f, 0.f, 0.f, 0.f);
  float4 a1 = a0, a2 = a0;
  for (int e = wave; e < mm; e += 4) {
    float pk = s_pc[e];
    const float4* vr4 = (const float4*)(W_val + (size_t)s_fc[e] * HD);
    float4 v0 = vr4[lane];
    float4 v1 = vr4[lane + 64];
    float4 v2 = vr4[lane + 128];
    a0.x += pk * v0.x; a0.y += pk * v0.y; a0.z += pk * v0.z; a0.w += pk * v0.w;
    a1.x += pk * v1.x; a1.y += pk * v1.y; a1.z += pk * v1.z; a1.w += pk * v1.w;
    a2.x += pk * v2.x; a2.y += pk * v2.y; a2.z += pk * v2.z; a2.w += pk * v2.w;
  }
  ((float4*)s_o[wave])[lane] = a0;
  ((float4*)s_o[wave])[lane + 64] = a1;
  ((float4*)s_o[wave])[lane + 128] = a2;
  __syncthreads();

  float* orow = o + (size_t)bq * HD;
  for (int h = tid; h < HD; h += 256)
    orow[h] = (s_o[0][h] + s_o[1][h]) + (s_o[2][h] + s_o[3][h]);
}

// Kernel 3a: column mean with !=0 count. grid (NB*6), each block 128 columns.
__global__ __launch_bounds__(256) void k_avg(
    const float* __restrict__ o, float* __restrict__ avg) {
  int b = blockIdx.x / 6, c = blockIdx.x % 6;
  int tid = threadIdx.x;
  int hc = tid & 127;
  int h = c * 128 + hc;
  int slice = tid >> 7;
  __shared__ float s_sum[2][128];
  __shared__ int s_cnt[2][128];
  float sum = 0.f;
  int cnt = 0;
#pragma unroll 8
  for (int q = slice * 64; q < (slice + 1) * 64; ++q) {
    float v = o[((size_t)(b * SL + q)) * HD + h];
    sum += v;
    cnt += (v != 0.f) ? 1 : 0;
  }
  s_sum[slice][hc] = sum;
  s_cnt[slice][hc] = cnt;
  __syncthreads();
  if (tid < 128) {
    float t = s_sum[0][tid] + s_sum[1][tid];
    int cc = s_cnt[0][tid] + s_cnt[1][tid];
    avg[(size_t)b * HD + c * 128 + tid] = t / (float)cc;  // IEEE inf/nan if cc==0, matches ref
  }
}

// Kernel 3b: logits = [pooled, avg] @ W_dense^T + b_dense
__global__ __launch_bounds__(192) void k_dense(
    const float* __restrict__ pooled,
    const float* __restrict__ avg,
    const float* __restrict__ W_dense,
    const float* __restrict__ b_dense,
    float* __restrict__ out) {
  int b = blockIdx.x;
  int tid = threadIdx.x;
  int n = tid >> 6, lane = tid & 63;
  float part = 0.f;
  for (int j = lane; j < HD; j += 64)
    part += pooled[(size_t)b * HD + j] * W_dense[(size_t)n * (2 * HD) + j];
  for (int j = lane; j < HD; j += 64)
    part += avg[(size_t)b * HD + j] * W_dense[(size_t)n * (2 * HD) + HD + j];
#pragma unroll
  for (int off = 32; off; off >>= 1) part += __shfl_xor(part, off);
  if (lane == 0) out[b * 3 + n] = part + b_dense[n];
}

extern "C" void kernel_launch(void* const* d_in, const int* in_sizes, int n_in,
                              void* d_out, int out_size, void* d_ws, size_t ws_size,
                              hipStream_t stream) {
  const float* seq     = (const float*)d_in[0];
  const float* pooled  = (const float*)d_in[1];
  const float* W_key   = (const float*)d_in[2];
  const float* W_val   = (const float*)d_in[3];
  const float* W_dense = (const float*)d_in[4];
  const float* b_dense = (const float*)d_in[5];
  const int* valid     = (const int*)d_in[6];
  const int* kvidx     = (const int*)d_in[7];
  const int* features  = (const int*)d_in[8];
  const int* pos       = (const int*)d_in[9];
  const int* aspect    = (const int*)d_in[10];
  float* out = (float*)d_out;

  float* hidden = (float*)d_ws;                       // [B,L,H]
  float* keyemb = hidden + (size_t)NB * SL * HD;      // [B,L,H]
  float* o      = keyemb + (size_t)NB * SL * HD;      // [B,L,H]
  float* avg    = o + (size_t)NB * SL * HD;           // [B,H]

  k_pack_gather<<<NB * SL, 256, 0, stream>>>(seq, W_key, valid, kvidx, aspect, hidden, keyemb);
  k_attend<<<NB * SL, 256, 0, stream>>>(hidden, keyemb, features, pos, W_val, o);
  k_avg<<<NB * 6, 256, 0, stream>>>(o, avg);
  k_dense<<<NB, 192, 0, stream>>>(pooled, avg, W_dense, b_dense, out);
}